// Round 7
// baseline (435.543 us; speedup 1.0000x reference)
//
#include <hip/hip_runtime.h>

// B=4, S=2048, D=1024, scale = 1/sqrt(64) = 0.125
// Workspace layout (105 MB):
//   [0,16M)    Xbf  : features bf16              [8192,1024]
//   [16M,24M)  Wcat bf16: Wq|Wk|Wv|Wo            4 x [1024,1024]
//   [24M,40M)  Q bf16 [8192,1024]  -> reused as attn
//   [40M,56M)  K bf16
//   [56M,72M)  Vt bf16 (V transposed)            [4][1024,2048]
//   [72M,104M) P~ bf16 dense [4][2048,2048]
//   [104M,+32K) lsum fp32 [8192]
//
// R13 = R6 + B-operand direct-to-register (LDS for A only).
// Evidence: QKV invariant ~90us / Mfma 23.5% across R0-R6 (occupancy 2-5
// blk, dbuf on/off, swizzle) -> limiter is the per-K-step serial chain
// {8 staged loads -> vmcnt drain -> 8 ds_read -> MFMA}. The MFMA B-frag is
// 8 CONTIGUOUS bf16 at B[wn+j*16+fr][k0+32s+8fq] -> one global dwordx4 per
// frag, loadable straight to VGPR. B leaves LDS: staging halves (4 loads),
// ds_read halves (4xb128), LDS 32->16 KB. 2-step unrolled ping-pong
// (bvA/bvB, compile-time indices only): next step's B loads issue after the
// barrier and drain at the post-MFMA syncthreads -> latency hidden under
// ~650 cyc of MFMA. Cost: B L2 traffic 2x (per-wave frags, no LDS share) —
// ~23us of 34.5 TB/s L2 BW on QKV, not binding; per-XCD B sets 2-6 MB.
// T1 swizzle kept from R6 (neutral alone; L2 pressure now higher).
//
// MODE 2: fp32 row-major + bias (out-proj)
// MODE 3: fused QKV epilogue (Q->C, K->C2, Vt->C3 transposed-batched)
// MODE 4: bf16 row-major, acc * 1/lsum[row] (PV normalize)
// MODE 5: exp(scale*acc) bf16 + atomic row sums (scores)

using u16 = unsigned short;
typedef __bf16 bf16x8 __attribute__((ext_vector_type(8)));
typedef float f32x4 __attribute__((ext_vector_type(4)));

#define AS1 __attribute__((address_space(1)))
#define AS3 __attribute__((address_space(3)))

__device__ inline u16 f2bf(float f) {
  union { float f; unsigned int u; } c; c.f = f;
  unsigned int u = c.u;
  u += 0x7fffu + ((u >> 16) & 1u);   // round-to-nearest-even
  return (u16)(u >> 16);
}

// one launch: casts features + all 4 weight matrices, and zeroes lsum
__global__ __launch_bounds__(256) void cast_all(
    const float4* __restrict__ feat, const float4* __restrict__ wq,
    const float4* __restrict__ wk, const float4* __restrict__ wv,
    const float4* __restrict__ wo, ushort4* __restrict__ xbf,
    ushort4* __restrict__ wcat, float* __restrict__ lsum) {
  const int b = blockIdx.x, tx = threadIdx.x;
  if (b >= 12288) {                      // 32 trailing blocks zero lsum[8192]
    lsum[(b - 12288) * 256 + tx] = 0.f;
    return;
  }
  const float4* src; ushort4* dst; int idx;
  if (b < 8192) { src = feat; dst = xbf; idx = b * 256 + tx; }
  else {
    const int w = (b - 8192) >> 10, loc = ((b - 8192) & 1023) * 256 + tx;
    src = (w == 0) ? wq : (w == 1) ? wk : (w == 2) ? wv : wo;
    dst = wcat + w * 262144; idx = loc;
  }
  float4 v = src[idx];
  ushort4 o;
  o.x = f2bf(v.x); o.y = f2bf(v.y); o.z = f2bf(v.z); o.w = f2bf(v.w);
  dst[idx] = o;
}

template <int MODE>
__global__ __launch_bounds__(256) void gemm_bt(
    const u16* __restrict__ A, const u16* __restrict__ Bm, void* __restrict__ C,
    void* __restrict__ C2, void* __restrict__ C3,
    const float* __restrict__ bias, const float* __restrict__ bias2,
    const float* __restrict__ bias3, float* __restrict__ lsum,
    int M, int N, int K, int lda, int ldc,
    float scale,
    long long sA, long long sB, long long sC)
{
  __shared__ u16 As[128 * 64];           // A tile only; B goes direct to regs
  const int tx = threadIdx.x;
  const int wave = tx >> 6, lane = tx & 63;
  const int wm = (wave >> 1) * 64, wn = (wave & 1) * 64;

  // XCD-aware bijective block swizzle (T1). All grids %8==0 -> bijection.
  const int nwg = gridDim.x * gridDim.y * gridDim.z;
  const int f = blockIdx.x + gridDim.x * (blockIdx.y + gridDim.y * blockIdx.z);
  const int w = (f & 7) * (nwg >> 3) + (f >> 3);
  const int bx = w % gridDim.x;
  const int rem = w / gridDim.x;
  const int by = rem % gridDim.y;
  const int bz = rem / gridDim.y;

  const int m0 = by * 128, n0 = bx * 128;
  const u16* Ab = A + bz * sA + (long long)m0 * lda;
  const u16* Bb = Bm + bz * sB + (long long)n0 * K;

  f32x4 acc[4][4] = {};

  // A staging: issue t in 0..3, chunk c = t*256 + wave*64 + lane (16B each)
  // r = c>>3; slot p = lane&7 holds logical quad q=(p-r)&7 (rotation swizzle)
  int rT[4], qT[4];
#pragma unroll
  for (int t = 0; t < 4; ++t) {
    rT[t] = t * 32 + wave * 8 + (lane >> 3);
    qT[t] = (((lane & 7) - rT[t]) & 7) << 3;   // element offset of 8-elem quad
  }
  const int ldsT[4] = {wave * 512, 2048 + wave * 512, 4096 + wave * 512,
                       6144 + wave * 512};

  const int fr = lane & 15, fq = lane >> 4;

  auto stageA = [&](int k0) {
#pragma unroll
    for (int t = 0; t < 4; ++t)
      __builtin_amdgcn_global_load_lds(
          (const AS1 void*)(Ab + (long long)rT[t] * lda + k0 + qT[t]),
          (AS3 void*)(As + ldsT[t]), 16, 0, 0);
  };
  // B fragments direct from global: row wn+j*16+fr, cols k0+32s+8fq (16B)
  auto loadB = [&](int k0, bf16x8 (&bv)[4][2]) {
#pragma unroll
    for (int j = 0; j < 4; ++j) {
      const u16* Brow = Bb + (long long)(wn + j * 16 + fr) * K + k0 + fq * 8;
#pragma unroll
      for (int s = 0; s < 2; ++s)
        bv[j][s] = *(const bf16x8*)(Brow + s * 32);
    }
  };
  auto compute = [&](const bf16x8 (&bv)[4][2]) {
#pragma unroll
    for (int s = 0; s < 2; ++s) {
      bf16x8 af[4];
#pragma unroll
      for (int i = 0; i < 4; ++i) {
        const int Ra = wm + i * 16 + fr;
        af[i] = *(const bf16x8*)(As + Ra * 64 + (((s * 4 + fq + Ra) & 7) << 3));
      }
#pragma unroll
      for (int i = 0; i < 4; ++i)
#pragma unroll
        for (int j = 0; j < 4; ++j)
          acc[i][j] = __builtin_amdgcn_mfma_f32_16x16x32_bf16(af[i], bv[j][s], acc[i][j], 0, 0, 0);
    }
  };

  bf16x8 bvA[4][2], bvB[4][2];
  loadB(0, bvA);
  // K is a multiple of 128 for all shapes here (1024 or 2048): 2-step unroll.
  for (int k0 = 0; k0 < K; k0 += 128) {
    // step 1: compute with bvA, prefetch bvB(k0+64)
    stageA(k0);
    __syncthreads();                       // A(k0) landed
    loadB(k0 + 64, bvB);                   // drains at next sync, under MFMA
    compute(bvA);
    __syncthreads();                       // LDS free + bvB landed

    // step 2: compute with bvB, prefetch bvA(k0+128)
    stageA(k0 + 64);
    __syncthreads();                       // A(k0+64) landed
    if (k0 + 128 < K) loadB(k0 + 128, bvA);
    compute(bvB);
    __syncthreads();
  }

  // epilogue: C/D layout col=lane&15, row=(lane>>4)*4+reg
  const int col = lane & 15, rq = (lane >> 4) << 2;
  const long long zC = (long long)bz * sC;

  if constexpr (MODE == 5) {
    // exp + bf16 store + per-row sum (reduce over 16 col-lanes, atomicAdd)
    float rsum[4][4] = {};   // [i][r]
#pragma unroll
    for (int i = 0; i < 4; ++i) {
#pragma unroll
      for (int j = 0; j < 4; ++j) {
        const int gn = n0 + wn + j * 16 + col;
#pragma unroll
        for (int r = 0; r < 4; ++r) {
          const int gm = m0 + wm + i * 16 + rq + r;
          const float e = __expf(acc[i][j][r] * scale);
          ((u16*)C)[zC + (long long)gm * ldc + gn] = f2bf(e);
          rsum[i][r] += e;
        }
      }
    }
#pragma unroll
    for (int i = 0; i < 4; ++i) {
#pragma unroll
      for (int r = 0; r < 4; ++r) {
        float s = rsum[i][r];
        s += __shfl_xor(s, 1); s += __shfl_xor(s, 2);
        s += __shfl_xor(s, 4); s += __shfl_xor(s, 8);
        if (col == 0)
          atomicAdd(&lsum[(long long)bz * 2048 + m0 + wm + i * 16 + rq + r], s);
      }
    }
  } else if constexpr (MODE == 4) {
    float inv[4][4];
#pragma unroll
    for (int i = 0; i < 4; ++i)
#pragma unroll
      for (int r = 0; r < 4; ++r)
        inv[i][r] = 1.0f / lsum[(long long)bz * 2048 + m0 + wm + i * 16 + rq + r];
#pragma unroll
    for (int i = 0; i < 4; ++i)
#pragma unroll
      for (int j = 0; j < 4; ++j) {
        const int gn = n0 + wn + j * 16 + col;
#pragma unroll
        for (int r = 0; r < 4; ++r) {
          const int gm = m0 + wm + i * 16 + rq + r;
          ((u16*)C)[zC + (long long)gm * ldc + gn] = f2bf(acc[i][j][r] * inv[i][r]);
        }
      }
  } else if constexpr (MODE == 3) {
    const int sect = n0 >> 10;  // 0=Q 1=K 2=V (n0 128-aligned, uniform)
#pragma unroll
    for (int i = 0; i < 4; ++i) {
#pragma unroll
      for (int j = 0; j < 4; ++j) {
        const int gn = n0 + wn + j * 16 + col;
        const int nb = gn & 1023;
        const float bv = (sect == 0) ? bias[nb] : (sect == 1) ? bias2[nb] : bias3[nb];
#pragma unroll
        for (int r = 0; r < 4; ++r) {
          const int gm = m0 + wm + i * 16 + rq + r;
          const float v = acc[i][j][r] + bv;
          if (sect == 0) {
            ((u16*)C)[(long long)gm * 1024 + nb] = f2bf(v);
          } else if (sect == 1) {
            ((u16*)C2)[(long long)gm * 1024 + nb] = f2bf(v);
          } else {
            const int bb = gm >> 11, t = gm & 2047;
            ((u16*)C3)[((long long)bb << 21) + (long long)nb * 2048 + t] = f2bf(v);
          }
        }
      }
    }
  } else {  // MODE == 2: fp32 row-major + bias
#pragma unroll
    for (int i = 0; i < 4; ++i) {
#pragma unroll
      for (int j = 0; j < 4; ++j) {
        const int gn = n0 + wn + j * 16 + col;
        const float bv = bias[gn];
#pragma unroll
        for (int r = 0; r < 4; ++r) {
          const int gm = m0 + wm + i * 16 + rq + r;
          ((float*)C)[zC + (long long)gm * ldc + gn] = acc[i][j][r] + bv;
        }
      }
    }
  }
}

extern "C" void kernel_launch(void* const* d_in, const int* in_sizes, int n_in,
                              void* d_out, int out_size, void* d_ws, size_t ws_size,
                              hipStream_t stream) {
  (void)in_sizes; (void)n_in; (void)out_size; (void)ws_size;
  const float* feat = (const float*)d_in[0];
  const float* Wq = (const float*)d_in[1];
  const float* bq = (const float*)d_in[2];
  const float* Wk = (const float*)d_in[3];
  const float* bk = (const float*)d_in[4];
  const float* Wv = (const float*)d_in[5];
  const float* bv = (const float*)d_in[6];
  const float* Wo = (const float*)d_in[7];
  const float* bo = (const float*)d_in[8];
  float* out = (float*)d_out;

  char* ws = (char*)d_ws;
  const unsigned long long MB = 1024ull * 1024ull;
  u16* Xbf  = (u16*)(ws);
  u16* Wcat = (u16*)(ws + 16 * MB);           // Wq|Wk|Wv|Wo bf16
  u16* Wob  = Wcat + 3ll * 1024 * 1024;
  u16* Q    = (u16*)(ws + 24 * MB);           // reused as attn later
  u16* Kbuf = (u16*)(ws + 40 * MB);
  u16* Vt   = (u16*)(ws + 56 * MB);
  u16* P    = (u16*)(ws + 72 * MB);           // dense bf16 [4][2048,2048]
  float* lsum = (float*)(ws + 104 * MB);      // [8192]
  u16* attn = Q;

  dim3 blk(256);

  // casts (features + 4 weights) + lsum zeroing in one launch
  cast_all<<<12320, blk, 0, stream>>>((const float4*)feat, (const float4*)Wq,
                                      (const float4*)Wk, (const float4*)Wv,
                                      (const float4*)Wo, (ushort4*)Xbf,
                                      (ushort4*)Wcat, lsum);

  // fused QKV projection: N=3072 over Wq|Wk|Wv; V written transposed per batch
  gemm_bt<3><<<dim3(24, 64, 1), blk, 0, stream>>>(
      Xbf, Wcat, Q, Kbuf, Vt, bq, bk, bv, nullptr,
      8192, 3072, 1024, 1024, 0, 1.f, 0, 0, 0);

  // P~ = exp(Q K^T * 0.125) bf16 + row sums -> lsum (all 4 batches)
  gemm_bt<5><<<dim3(16, 16, 4), blk, 0, stream>>>(
      Q, Kbuf, P, nullptr, nullptr, nullptr, nullptr, nullptr, lsum,
      2048, 2048, 1024, 1024, 2048, 0.125f,
      2048ll * 1024, 2048ll * 1024, 2048ll * 2048);

  // attn = (P~ @ V) / lsum  (batched; B operand is Vt)
  gemm_bt<4><<<dim3(8, 16, 4), blk, 0, stream>>>(
      P, Vt, attn, nullptr, nullptr, nullptr, nullptr, nullptr, lsum,
      2048, 1024, 2048, 2048, 1024, 1.f,
      2048ll * 2048, 1024ll * 2048, 2048ll * 1024);

  // out = attn @ Wo^T + bo  (fp32 output)
  gemm_bt<2><<<dim3(8, 64, 1), blk, 0, stream>>>(
      attn, Wob, out, nullptr, nullptr, bo, nullptr, nullptr, nullptr,
      8192, 1024, 1024, 1024, 1024, 1.f, 0, 0, 0);
}

// Round 8
// 343.375 us; speedup vs baseline: 1.2684x; 1.2684x over previous
//
#include <hip/hip_runtime.h>

// B=4, S=2048, D=1024, scale = 1/sqrt(64) = 0.125
// Workspace layout (105 MB):
//   [0,16M)    Xbf  : features bf16              [8192,1024]
//   [16M,24M)  Wcat bf16: Wq|Wk|Wv|Wo            4 x [1024,1024]
//   [24M,40M)  Q bf16 [8192,1024]  -> reused as attn
//   [40M,56M)  K bf16
//   [56M,72M)  Vt bf16 (V transposed)            [4][1024,2048]
//   [72M,104M) P~ bf16 dense [4][2048,2048]
//   [104M,+32K) lsum fp32 [8192]
//
// R14 = R0 exactly, with BK 64->32 single-buffered (LDS 32->16 KB/block).
// Session A/B series isolated residency as the binding knob: QKV time
// orders by LDS-implied blocks/CU (R0 32KB/5blk: 90.7us > R3 64KB/2blk:
// 98.6 > R2 128KB/1blk: 108), and R3's textbook dbuf LOST -> R0's per-step
// drains are already TLP-hidden; the derived OccupancyPercent (~24%) is a
// gfx94x-fallback formula and inconsistent with that ordering. BK=32 at
// 16 KB lifts the LDS cap to 10 blocks; VGPR(80) then binds at 6 waves/SIMD
// = 6 blocks/CU (+20% TLP vs 5). Staged bytes, gload_lds count, and
// ds_read:MFMA ratio are conserved; only barriers double (TLP amortizes).
// The proven 8-slot rotation swizzle carries over via row-packing the
// [128]x[32] tile into LDS [64]x[64]: Apk[r&63][(r>>6)*32 + c]; staging
// source pre-rotated with the same inverse; read slot =
// ((R>>6)*4 + fq + (R&63)) & 7  -> same conflict profile as R0 (measured 0).
// R7's B-direct (scattered per-lane loads) and R6's T1 swizzle (neutral)
// both reverted: this is a one-variable delta on the measured-best R0.
//
// MODE 2: fp32 row-major + bias (out-proj)
// MODE 3: fused QKV epilogue (Q->C, K->C2, Vt->C3 transposed-batched)
// MODE 4: bf16 row-major, acc * 1/lsum[row] (PV normalize)
// MODE 5: exp(scale*acc) bf16 + atomic row sums (scores)

using u16 = unsigned short;
typedef __bf16 bf16x8 __attribute__((ext_vector_type(8)));
typedef float f32x4 __attribute__((ext_vector_type(4)));

#define AS1 __attribute__((address_space(1)))
#define AS3 __attribute__((address_space(3)))

__device__ inline u16 f2bf(float f) {
  union { float f; unsigned int u; } c; c.f = f;
  unsigned int u = c.u;
  u += 0x7fffu + ((u >> 16) & 1u);   // round-to-nearest-even
  return (u16)(u >> 16);
}

// one launch: casts features + all 4 weight matrices, and zeroes lsum
__global__ __launch_bounds__(256) void cast_all(
    const float4* __restrict__ feat, const float4* __restrict__ wq,
    const float4* __restrict__ wk, const float4* __restrict__ wv,
    const float4* __restrict__ wo, ushort4* __restrict__ xbf,
    ushort4* __restrict__ wcat, float* __restrict__ lsum) {
  const int b = blockIdx.x, tx = threadIdx.x;
  if (b >= 12288) {                      // 32 trailing blocks zero lsum[8192]
    lsum[(b - 12288) * 256 + tx] = 0.f;
    return;
  }
  const float4* src; ushort4* dst; int idx;
  if (b < 8192) { src = feat; dst = xbf; idx = b * 256 + tx; }
  else {
    const int w = (b - 8192) >> 10, loc = ((b - 8192) & 1023) * 256 + tx;
    src = (w == 0) ? wq : (w == 1) ? wk : (w == 2) ? wv : wo;
    dst = wcat + w * 262144; idx = loc;
  }
  float4 v = src[idx];
  ushort4 o;
  o.x = f2bf(v.x); o.y = f2bf(v.y); o.z = f2bf(v.z); o.w = f2bf(v.w);
  dst[idx] = o;
}

template <int MODE>
__global__ __launch_bounds__(256) void gemm_bt(
    const u16* __restrict__ A, const u16* __restrict__ Bm, void* __restrict__ C,
    void* __restrict__ C2, void* __restrict__ C3,
    const float* __restrict__ bias, const float* __restrict__ bias2,
    const float* __restrict__ bias3, float* __restrict__ lsum,
    int M, int N, int K, int lda, int ldc,
    float scale,
    long long sA, long long sB, long long sC)
{
  // packed [64][64] per matrix: row r, cols 0..31 -> Apk[r&63][(r>>6)*32..]
  __shared__ u16 As[64 * 64];
  __shared__ u16 Bs[64 * 64];
  const int tx = threadIdx.x;
  const int wave = tx >> 6, lane = tx & 63;
  const int wm = (wave >> 1) * 64, wn = (wave & 1) * 64;
  const int m0 = blockIdx.y * 128, n0 = blockIdx.x * 128;
  const u16* Ab = A + blockIdx.z * sA + (long long)m0 * lda;
  const u16* Bb = Bm + blockIdx.z * sB + (long long)n0 * K;

  f32x4 acc[4][4] = {};

  // staging: issue t in {0,1}, chunk ch = t*256 + wave*64 + lane (16B each).
  // packed row = ch>>3 (0..63), phys slot p = lane&7; logical quad
  // q = (p - row)&7; source: global row = row + 64*(q>>2), col = (q&3)*8.
  int rT[2], sT[2];
#pragma unroll
  for (int t = 0; t < 2; ++t) {
    const int row = t * 32 + wave * 8 + (lane >> 3);
    const int q = ((lane & 7) - row) & 7;
    rT[t] = row + ((q >> 2) << 6);
    sT[t] = (q & 3) << 3;
  }
  // wave-uniform LDS dest base for issue t (HW adds lane*16B)
  const int ldsT[2] = {wave * 512, 2048 + wave * 512};

  const int fr = lane & 15, fq = lane >> 4;

  auto stage = [&](int k0) {
#pragma unroll
    for (int t = 0; t < 2; ++t) {
      __builtin_amdgcn_global_load_lds(
          (const AS1 void*)(Ab + (long long)rT[t] * lda + k0 + sT[t]),
          (AS3 void*)(As + ldsT[t]), 16, 0, 0);
      __builtin_amdgcn_global_load_lds(
          (const AS1 void*)(Bb + (long long)rT[t] * K + k0 + sT[t]),
          (AS3 void*)(Bs + ldsT[t]), 16, 0, 0);
    }
  };

  for (int k0 = 0; k0 < K; k0 += 32) {
    stage(k0);
    __syncthreads();

    bf16x8 af[4], bfv[4];
#pragma unroll
    for (int i = 0; i < 4; ++i) {
      const int Ra = wm + i * 16 + fr;
      const int Rb = wn + i * 16 + fr;
      const int pa = Ra & 63, pb = Rb & 63;
      const int sa = (((Ra >> 6) * 4 + fq + pa) & 7) << 3;
      const int sb = (((Rb >> 6) * 4 + fq + pb) & 7) << 3;
      af[i]  = *(const bf16x8*)(As + pa * 64 + sa);
      bfv[i] = *(const bf16x8*)(Bs + pb * 64 + sb);
    }
#pragma unroll
    for (int i = 0; i < 4; ++i)
#pragma unroll
      for (int j = 0; j < 4; ++j)
        acc[i][j] = __builtin_amdgcn_mfma_f32_16x16x32_bf16(af[i], bfv[j], acc[i][j], 0, 0, 0);
    __syncthreads();
  }

  // epilogue: C/D layout col=lane&15, row=(lane>>4)*4+reg
  const int col = lane & 15, rq = (lane >> 4) << 2;
  const long long zC = (long long)blockIdx.z * sC;

  if constexpr (MODE == 5) {
    // exp + bf16 store + per-row sum (reduce over 16 col-lanes, atomicAdd)
    float rsum[4][4] = {};   // [i][r]
#pragma unroll
    for (int i = 0; i < 4; ++i) {
#pragma unroll
      for (int j = 0; j < 4; ++j) {
        const int gn = n0 + wn + j * 16 + col;
#pragma unroll
        for (int r = 0; r < 4; ++r) {
          const int gm = m0 + wm + i * 16 + rq + r;
          const float e = __expf(acc[i][j][r] * scale);
          ((u16*)C)[zC + (long long)gm * ldc + gn] = f2bf(e);
          rsum[i][r] += e;
        }
      }
    }
#pragma unroll
    for (int i = 0; i < 4; ++i) {
#pragma unroll
      for (int r = 0; r < 4; ++r) {
        float s = rsum[i][r];
        s += __shfl_xor(s, 1); s += __shfl_xor(s, 2);
        s += __shfl_xor(s, 4); s += __shfl_xor(s, 8);
        if (col == 0)
          atomicAdd(&lsum[(long long)blockIdx.z * 2048 + m0 + wm + i * 16 + rq + r], s);
      }
    }
  } else if constexpr (MODE == 4) {
    float inv[4][4];
#pragma unroll
    for (int i = 0; i < 4; ++i)
#pragma unroll
      for (int r = 0; r < 4; ++r)
        inv[i][r] = 1.0f / lsum[(long long)blockIdx.z * 2048 + m0 + wm + i * 16 + rq + r];
#pragma unroll
    for (int i = 0; i < 4; ++i)
#pragma unroll
      for (int j = 0; j < 4; ++j) {
        const int gn = n0 + wn + j * 16 + col;
#pragma unroll
        for (int r = 0; r < 4; ++r) {
          const int gm = m0 + wm + i * 16 + rq + r;
          ((u16*)C)[zC + (long long)gm * ldc + gn] = f2bf(acc[i][j][r] * inv[i][r]);
        }
      }
  } else if constexpr (MODE == 3) {
    const int sect = n0 >> 10;  // 0=Q 1=K 2=V (n0 128-aligned, uniform)
#pragma unroll
    for (int i = 0; i < 4; ++i) {
#pragma unroll
      for (int j = 0; j < 4; ++j) {
        const int gn = n0 + wn + j * 16 + col;
        const int nb = gn & 1023;
        const float bv = (sect == 0) ? bias[nb] : (sect == 1) ? bias2[nb] : bias3[nb];
#pragma unroll
        for (int r = 0; r < 4; ++r) {
          const int gm = m0 + wm + i * 16 + rq + r;
          const float v = acc[i][j][r] + bv;
          if (sect == 0) {
            ((u16*)C)[(long long)gm * 1024 + nb] = f2bf(v);
          } else if (sect == 1) {
            ((u16*)C2)[(long long)gm * 1024 + nb] = f2bf(v);
          } else {
            const int bb = gm >> 11, t = gm & 2047;
            ((u16*)C3)[((long long)bb << 21) + (long long)nb * 2048 + t] = f2bf(v);
          }
        }
      }
    }
  } else {  // MODE == 2: fp32 row-major + bias
#pragma unroll
    for (int i = 0; i < 4; ++i) {
#pragma unroll
      for (int j = 0; j < 4; ++j) {
        const int gn = n0 + wn + j * 16 + col;
        const float bv = bias[gn];
#pragma unroll
        for (int r = 0; r < 4; ++r) {
          const int gm = m0 + wm + i * 16 + rq + r;
          ((float*)C)[zC + (long long)gm * ldc + gn] = acc[i][j][r] + bv;
        }
      }
    }
  }
}

extern "C" void kernel_launch(void* const* d_in, const int* in_sizes, int n_in,
                              void* d_out, int out_size, void* d_ws, size_t ws_size,
                              hipStream_t stream) {
  (void)in_sizes; (void)n_in; (void)out_size; (void)ws_size;
  const float* feat = (const float*)d_in[0];
  const float* Wq = (const float*)d_in[1];
  const float* bq = (const float*)d_in[2];
  const float* Wk = (const float*)d_in[3];
  const float* bk = (const float*)d_in[4];
  const float* Wv = (const float*)d_in[5];
  const float* bv = (const float*)d_in[6];
  const float* Wo = (const float*)d_in[7];
  const float* bo = (const float*)d_in[8];
  float* out = (float*)d_out;

  char* ws = (char*)d_ws;
  const unsigned long long MB = 1024ull * 1024ull;
  u16* Xbf  = (u16*)(ws);
  u16* Wcat = (u16*)(ws + 16 * MB);           // Wq|Wk|Wv|Wo bf16
  u16* Wob  = Wcat + 3ll * 1024 * 1024;
  u16* Q    = (u16*)(ws + 24 * MB);           // reused as attn later
  u16* Kbuf = (u16*)(ws + 40 * MB);
  u16* Vt   = (u16*)(ws + 56 * MB);
  u16* P    = (u16*)(ws + 72 * MB);           // dense bf16 [4][2048,2048]
  float* lsum = (float*)(ws + 104 * MB);      // [8192]
  u16* attn = Q;

  dim3 blk(256);

  // casts (features + 4 weights) + lsum zeroing in one launch
  cast_all<<<12320, blk, 0, stream>>>((const float4*)feat, (const float4*)Wq,
                                      (const float4*)Wk, (const float4*)Wv,
                                      (const float4*)Wo, (ushort4*)Xbf,
                                      (ushort4*)Wcat, lsum);

  // fused QKV projection: N=3072 over Wq|Wk|Wv; V written transposed per batch
  gemm_bt<3><<<dim3(24, 64, 1), blk, 0, stream>>>(
      Xbf, Wcat, Q, Kbuf, Vt, bq, bk, bv, nullptr,
      8192, 3072, 1024, 1024, 0, 1.f, 0, 0, 0);

  // P~ = exp(Q K^T * 0.125) bf16 + row sums -> lsum (all 4 batches)
  gemm_bt<5><<<dim3(16, 16, 4), blk, 0, stream>>>(
      Q, Kbuf, P, nullptr, nullptr, nullptr, nullptr, nullptr, lsum,
      2048, 2048, 1024, 1024, 2048, 0.125f,
      2048ll * 1024, 2048ll * 1024, 2048ll * 2048);

  // attn = (P~ @ V) / lsum  (batched; B operand is Vt)
  gemm_bt<4><<<dim3(8, 16, 4), blk, 0, stream>>>(
      P, Vt, attn, nullptr, nullptr, nullptr, nullptr, nullptr, lsum,
      2048, 1024, 2048, 2048, 1024, 1.f,
      2048ll * 2048, 1024ll * 2048, 2048ll * 1024);

  // out = attn @ Wo^T + bo  (fp32 output)
  gemm_bt<2><<<dim3(8, 64, 1), blk, 0, stream>>>(
      attn, Wob, out, nullptr, nullptr, bo, nullptr, nullptr, nullptr,
      8192, 1024, 1024, 1024, 1024, 1.f, 0, 0, 0);
}

// Round 9
// 328.095 us; speedup vs baseline: 1.3275x; 1.0466x over previous
//
#include <hip/hip_runtime.h>

// B=4, S=2048, D=1024, scale = 1/sqrt(64) = 0.125
// Workspace layout (105 MB):
//   [0,16M)    Xbf  : features bf16              [8192,1024]
//   [16M,24M)  Wcat bf16: Wq|Wk|Wv|Wo            4 x [1024,1024]
//   [24M,40M)  Q bf16 [8192,1024]  -> reused as attn
//   [40M,56M)  K bf16
//   [56M,72M)  Vt bf16 (V transposed)            [4][1024,2048]
//   [72M,104M) P~ bf16 dense [4][2048,2048]
//   [104M,+32K) lsum fp32 [8192]
//
// R15: BK=32 DOUBLE-buffered, one barrier + one deferred vmcnt(0) per step.
// Session A/B isolated two factors that never coexisted: TLP (R0 32KB/5blk:
// 90.7us beats R3 64KB/2blk: 98.6) and drain-hiding (R3 hid the staging
// drain behind compute; R0/R8 expose it before every compute: R8's 32
// exposed drains -> 101us despite 6blk). BK=32 dbuf = 32 KB (R0's footprint,
// 5 blk/CU) AND hides the drain:
//   iter t: vmcnt(0)  <- tile t's 4 loads, issued last iter, had a full
//                        compute phase (~500cyc) to land -> near-zero wait
//           s_barrier <- tile t visible; all waves done reading buf^1
//                        (their iter t-1 ds_reads complete before MFMA issue,
//                        hence before barrier arrival)
//           stage(t+1 -> buf^1)   WAR-safe behind the barrier
//           8 ds_read + 16 MFMA on buf;  buf ^= 1
// 32 barriers total = R0's 2x16; ds_read/gload counts = R0. Only deltas vs
// R0: drain hidden, R8 swizzle. R8's packed-[64][64] rotation swizzle kept:
// measured 0 bank conflicts. No in-loop vmem besides the 4 stages, so
// vmcnt(0) == counted wait on exactly tile t.
//
// MODE 2: fp32 row-major + bias (out-proj)
// MODE 3: fused QKV epilogue (Q->C, K->C2, Vt->C3 transposed-batched)
// MODE 4: bf16 row-major, acc * 1/lsum[row] (PV normalize)
// MODE 5: exp(scale*acc) bf16 + atomic row sums (scores)

using u16 = unsigned short;
typedef __bf16 bf16x8 __attribute__((ext_vector_type(8)));
typedef float f32x4 __attribute__((ext_vector_type(4)));

#define AS1 __attribute__((address_space(1)))
#define AS3 __attribute__((address_space(3)))

__device__ inline u16 f2bf(float f) {
  union { float f; unsigned int u; } c; c.f = f;
  unsigned int u = c.u;
  u += 0x7fffu + ((u >> 16) & 1u);   // round-to-nearest-even
  return (u16)(u >> 16);
}

// one launch: casts features + all 4 weight matrices, and zeroes lsum
__global__ __launch_bounds__(256) void cast_all(
    const float4* __restrict__ feat, const float4* __restrict__ wq,
    const float4* __restrict__ wk, const float4* __restrict__ wv,
    const float4* __restrict__ wo, ushort4* __restrict__ xbf,
    ushort4* __restrict__ wcat, float* __restrict__ lsum) {
  const int b = blockIdx.x, tx = threadIdx.x;
  if (b >= 12288) {                      // 32 trailing blocks zero lsum[8192]
    lsum[(b - 12288) * 256 + tx] = 0.f;
    return;
  }
  const float4* src; ushort4* dst; int idx;
  if (b < 8192) { src = feat; dst = xbf; idx = b * 256 + tx; }
  else {
    const int w = (b - 8192) >> 10, loc = ((b - 8192) & 1023) * 256 + tx;
    src = (w == 0) ? wq : (w == 1) ? wk : (w == 2) ? wv : wo;
    dst = wcat + w * 262144; idx = loc;
  }
  float4 v = src[idx];
  ushort4 o;
  o.x = f2bf(v.x); o.y = f2bf(v.y); o.z = f2bf(v.z); o.w = f2bf(v.w);
  dst[idx] = o;
}

template <int MODE>
__global__ __launch_bounds__(256) void gemm_bt(
    const u16* __restrict__ A, const u16* __restrict__ Bm, void* __restrict__ C,
    void* __restrict__ C2, void* __restrict__ C3,
    const float* __restrict__ bias, const float* __restrict__ bias2,
    const float* __restrict__ bias3, float* __restrict__ lsum,
    int M, int N, int K, int lda, int ldc,
    float scale,
    long long sA, long long sB, long long sC)
{
  // packed [64][64] per matrix per buffer: row r, cols 0..31 of the 128x32
  // K-tile -> pk[r&63][(r>>6)*32 + c]  (R8 layout, measured 0 conflicts)
  __shared__ u16 As[2 * 64 * 64];
  __shared__ u16 Bs[2 * 64 * 64];
  const int tx = threadIdx.x;
  const int wave = tx >> 6, lane = tx & 63;
  const int wm = (wave >> 1) * 64, wn = (wave & 1) * 64;
  const int m0 = blockIdx.y * 128, n0 = blockIdx.x * 128;
  const u16* Ab = A + blockIdx.z * sA + (long long)m0 * lda;
  const u16* Bb = Bm + blockIdx.z * sB + (long long)n0 * K;

  f32x4 acc[4][4] = {};

  // staging: issue t in {0,1}, chunk ch = t*256 + wave*64 + lane (16B each).
  // packed row = ch>>3 (0..63), phys slot p = lane&7; logical quad
  // q = (p - row)&7; source: global row = row + 64*(q>>2), col = (q&3)*8.
  int rT[2], sT[2];
#pragma unroll
  for (int t = 0; t < 2; ++t) {
    const int row = t * 32 + wave * 8 + (lane >> 3);
    const int q = ((lane & 7) - row) & 7;
    rT[t] = row + ((q >> 2) << 6);
    sT[t] = (q & 3) << 3;
  }
  // wave-uniform LDS dest base for issue t (HW adds lane*16B)
  const int ldsT[2] = {wave * 512, 2048 + wave * 512};

  const int fr = lane & 15, fq = lane >> 4;

  auto stage = [&](int k0, int buf) {
#pragma unroll
    for (int t = 0; t < 2; ++t) {
      __builtin_amdgcn_global_load_lds(
          (const AS1 void*)(Ab + (long long)rT[t] * lda + k0 + sT[t]),
          (AS3 void*)(As + buf * 4096 + ldsT[t]), 16, 0, 0);
      __builtin_amdgcn_global_load_lds(
          (const AS1 void*)(Bb + (long long)rT[t] * K + k0 + sT[t]),
          (AS3 void*)(Bs + buf * 4096 + ldsT[t]), 16, 0, 0);
    }
  };

  // prologue: tile 0 into buf 0 (its wait happens at iter 0's vmcnt)
  stage(0, 0);

  int cur = 0;
  for (int k0 = 0; k0 < K; k0 += 32) {
    // tile (k0)'s 4 loads are the only outstanding vmem: counted wait.
    asm volatile("s_waitcnt vmcnt(0)" ::: "memory");
    __builtin_amdgcn_s_barrier();
    if (k0 + 32 < K) stage(k0 + 32, cur ^ 1);

    const u16* Ac = As + cur * 4096;
    const u16* Bc = Bs + cur * 4096;
    bf16x8 af[4], bfv[4];
#pragma unroll
    for (int i = 0; i < 4; ++i) {
      const int Ra = wm + i * 16 + fr;
      const int Rb = wn + i * 16 + fr;
      const int pa = Ra & 63, pb = Rb & 63;
      const int sa = (((Ra >> 6) * 4 + fq + pa) & 7) << 3;
      const int sb = (((Rb >> 6) * 4 + fq + pb) & 7) << 3;
      af[i]  = *(const bf16x8*)(Ac + pa * 64 + sa);
      bfv[i] = *(const bf16x8*)(Bc + pb * 64 + sb);
    }
#pragma unroll
    for (int i = 0; i < 4; ++i)
#pragma unroll
      for (int j = 0; j < 4; ++j)
        acc[i][j] = __builtin_amdgcn_mfma_f32_16x16x32_bf16(af[i], bfv[j], acc[i][j], 0, 0, 0);
    cur ^= 1;
  }

  // epilogue: C/D layout col=lane&15, row=(lane>>4)*4+reg
  const int col = lane & 15, rq = (lane >> 4) << 2;
  const long long zC = (long long)blockIdx.z * sC;

  if constexpr (MODE == 5) {
    // exp + bf16 store + per-row sum (reduce over 16 col-lanes, atomicAdd)
    float rsum[4][4] = {};   // [i][r]
#pragma unroll
    for (int i = 0; i < 4; ++i) {
#pragma unroll
      for (int j = 0; j < 4; ++j) {
        const int gn = n0 + wn + j * 16 + col;
#pragma unroll
        for (int r = 0; r < 4; ++r) {
          const int gm = m0 + wm + i * 16 + rq + r;
          const float e = __expf(acc[i][j][r] * scale);
          ((u16*)C)[zC + (long long)gm * ldc + gn] = f2bf(e);
          rsum[i][r] += e;
        }
      }
    }
#pragma unroll
    for (int i = 0; i < 4; ++i) {
#pragma unroll
      for (int r = 0; r < 4; ++r) {
        float s = rsum[i][r];
        s += __shfl_xor(s, 1); s += __shfl_xor(s, 2);
        s += __shfl_xor(s, 4); s += __shfl_xor(s, 8);
        if (col == 0)
          atomicAdd(&lsum[(long long)blockIdx.z * 2048 + m0 + wm + i * 16 + rq + r], s);
      }
    }
  } else if constexpr (MODE == 4) {
    float inv[4][4];
#pragma unroll
    for (int i = 0; i < 4; ++i)
#pragma unroll
      for (int r = 0; r < 4; ++r)
        inv[i][r] = 1.0f / lsum[(long long)blockIdx.z * 2048 + m0 + wm + i * 16 + rq + r];
#pragma unroll
    for (int i = 0; i < 4; ++i)
#pragma unroll
      for (int j = 0; j < 4; ++j) {
        const int gn = n0 + wn + j * 16 + col;
#pragma unroll
        for (int r = 0; r < 4; ++r) {
          const int gm = m0 + wm + i * 16 + rq + r;
          ((u16*)C)[zC + (long long)gm * ldc + gn] = f2bf(acc[i][j][r] * inv[i][r]);
        }
      }
  } else if constexpr (MODE == 3) {
    const int sect = n0 >> 10;  // 0=Q 1=K 2=V (n0 128-aligned, uniform)
#pragma unroll
    for (int i = 0; i < 4; ++i) {
#pragma unroll
      for (int j = 0; j < 4; ++j) {
        const int gn = n0 + wn + j * 16 + col;
        const int nb = gn & 1023;
        const float bv = (sect == 0) ? bias[nb] : (sect == 1) ? bias2[nb] : bias3[nb];
#pragma unroll
        for (int r = 0; r < 4; ++r) {
          const int gm = m0 + wm + i * 16 + rq + r;
          const float v = acc[i][j][r] + bv;
          if (sect == 0) {
            ((u16*)C)[(long long)gm * 1024 + nb] = f2bf(v);
          } else if (sect == 1) {
            ((u16*)C2)[(long long)gm * 1024 + nb] = f2bf(v);
          } else {
            const int bb = gm >> 11, t = gm & 2047;
            ((u16*)C3)[((long long)bb << 21) + (long long)nb * 2048 + t] = f2bf(v);
          }
        }
      }
    }
  } else {  // MODE == 2: fp32 row-major + bias
#pragma unroll
    for (int i = 0; i < 4; ++i) {
#pragma unroll
      for (int j = 0; j < 4; ++j) {
        const int gn = n0 + wn + j * 16 + col;
        const float bv = bias[gn];
#pragma unroll
        for (int r = 0; r < 4; ++r) {
          const int gm = m0 + wm + i * 16 + rq + r;
          ((float*)C)[zC + (long long)gm * ldc + gn] = acc[i][j][r] + bv;
        }
      }
    }
  }
}

extern "C" void kernel_launch(void* const* d_in, const int* in_sizes, int n_in,
                              void* d_out, int out_size, void* d_ws, size_t ws_size,
                              hipStream_t stream) {
  (void)in_sizes; (void)n_in; (void)out_size; (void)ws_size;
  const float* feat = (const float*)d_in[0];
  const float* Wq = (const float*)d_in[1];
  const float* bq = (const float*)d_in[2];
  const float* Wk = (const float*)d_in[3];
  const float* bk = (const float*)d_in[4];
  const float* Wv = (const float*)d_in[5];
  const float* bv = (const float*)d_in[6];
  const float* Wo = (const float*)d_in[7];
  const float* bo = (const float*)d_in[8];
  float* out = (float*)d_out;

  char* ws = (char*)d_ws;
  const unsigned long long MB = 1024ull * 1024ull;
  u16* Xbf  = (u16*)(ws);
  u16* Wcat = (u16*)(ws + 16 * MB);           // Wq|Wk|Wv|Wo bf16
  u16* Wob  = Wcat + 3ll * 1024 * 1024;
  u16* Q    = (u16*)(ws + 24 * MB);           // reused as attn later
  u16* Kbuf = (u16*)(ws + 40 * MB);
  u16* Vt   = (u16*)(ws + 56 * MB);
  u16* P    = (u16*)(ws + 72 * MB);           // dense bf16 [4][2048,2048]
  float* lsum = (float*)(ws + 104 * MB);      // [8192]
  u16* attn = Q;

  dim3 blk(256);

  // casts (features + 4 weights) + lsum zeroing in one launch
  cast_all<<<12320, blk, 0, stream>>>((const float4*)feat, (const float4*)Wq,
                                      (const float4*)Wk, (const float4*)Wv,
                                      (const float4*)Wo, (ushort4*)Xbf,
                                      (ushort4*)Wcat, lsum);

  // fused QKV projection: N=3072 over Wq|Wk|Wv; V written transposed per batch
  gemm_bt<3><<<dim3(24, 64, 1), blk, 0, stream>>>(
      Xbf, Wcat, Q, Kbuf, Vt, bq, bk, bv, nullptr,
      8192, 3072, 1024, 1024, 0, 1.f, 0, 0, 0);

  // P~ = exp(Q K^T * 0.125) bf16 + row sums -> lsum (all 4 batches)
  gemm_bt<5><<<dim3(16, 16, 4), blk, 0, stream>>>(
      Q, Kbuf, P, nullptr, nullptr, nullptr, nullptr, nullptr, lsum,
      2048, 2048, 1024, 1024, 2048, 0.125f,
      2048ll * 1024, 2048ll * 1024, 2048ll * 2048);

  // attn = (P~ @ V) / lsum  (batched; B operand is Vt)
  gemm_bt<4><<<dim3(8, 16, 4), blk, 0, stream>>>(
      P, Vt, attn, nullptr, nullptr, nullptr, nullptr, nullptr, lsum,
      2048, 1024, 2048, 2048, 1024, 1.f,
      2048ll * 2048, 1024ll * 2048, 2048ll * 1024);

  // out = attn @ Wo^T + bo  (fp32 output)
  gemm_bt<2><<<dim3(8, 64, 1), blk, 0, stream>>>(
      attn, Wob, out, nullptr, nullptr, bo, nullptr, nullptr, nullptr,
      8192, 1024, 1024, 1024, 1024, 1.f, 0, 0, 0);
}